// Round 5
// baseline (536.187 us; speedup 1.0000x reference)
//
#include <hip/hip_runtime.h>
#include <hip/hip_bf16.h>
#include <stdint.h>

typedef __attribute__((ext_vector_type(8))) short short8;
typedef __attribute__((ext_vector_type(4))) float floatx4;

// Q pre-scale: 0.125 (1/sqrt(K)) * log2(e), so exp(s/8) == exp2(q'.k)
#define QSCALE 0.18033688f

__device__ __forceinline__ unsigned short f2bf(float f) {
    unsigned int u = __float_as_uint(f);
    u += 0x7fffu + ((u >> 16) & 1u);
    return (unsigned short)(u >> 16);
}
__device__ __forceinline__ unsigned int pack2bf(float a, float b) {
    __hip_bfloat162 h = __float22bfloat162_rn(make_float2(a, b));
    return *reinterpret_cast<unsigned int*>(&h);
}

// ---------------------------------------------------------------------------
// cvt: fp32 -> bf16, 8 elements/thread
// ---------------------------------------------------------------------------
__global__ __launch_bounds__(256) void cvt_bf16(const float* __restrict__ src,
                                                unsigned short* __restrict__ dst, int n8) {
    int i = blockIdx.x * 256 + threadIdx.x;
    if (i >= n8) return;
    const float4 a = ((const float4*)src)[2 * i];
    const float4 b = ((const float4*)src)[2 * i + 1];
    ushort4 lo, hi;
    lo.x = f2bf(a.x); lo.y = f2bf(a.y); lo.z = f2bf(a.z); lo.w = f2bf(a.w);
    hi.x = f2bf(b.x); hi.y = f2bf(b.y); hi.z = f2bf(b.z); hi.w = f2bf(b.w);
    ((ushort4*)dst)[2 * i] = lo;
    ((ushort4*)dst)[2 * i + 1] = hi;
}

// ---------------------------------------------------------------------------
// tcvt: fp32 [R][C] -> bf16 [C][R]  (64x64 tiles via LDS)
// ---------------------------------------------------------------------------
__global__ __launch_bounds__(256) void tcvt(const float* __restrict__ src,
                                            unsigned short* __restrict__ dst, int R, int C) {
    __shared__ unsigned short t[64][72];
    const int tid = threadIdx.x;
    const int r0 = blockIdx.y * 64, c0 = blockIdx.x * 64;
    #pragma unroll
    for (int it = 0; it < 4; it++) {
        int idx = it * 256 + tid;
        int rr = idx >> 4, cc = (idx & 15) * 4;
        float4 v = *(const float4*)(src + (size_t)(r0 + rr) * C + c0 + cc);
        t[cc + 0][rr] = f2bf(v.x);
        t[cc + 1][rr] = f2bf(v.y);
        t[cc + 2][rr] = f2bf(v.z);
        t[cc + 3][rr] = f2bf(v.w);
    }
    __syncthreads();
    #pragma unroll
    for (int it = 0; it < 2; it++) {
        int idx = it * 256 + tid;
        int cc = idx >> 3, r8 = (idx & 7) * 8;
        short8 v = *(const short8*)&t[cc][r8];
        *(short8*)(dst + (size_t)(c0 + cc) * R + r0 + r8) = v;
    }
}

// ---------------------------------------------------------------------------
// vtrans: vb[bh][2048][64] -> vbt[bh][64][2048]  (64x64 tiles via LDS)
// ---------------------------------------------------------------------------
__global__ __launch_bounds__(256) void vtrans(const unsigned short* __restrict__ vb,
                                              unsigned short* __restrict__ vbt) {
    __shared__ unsigned short t[64][72];
    const int tid = threadIdx.x;
    const int bh = blockIdx.y, m0 = blockIdx.x * 64;
    const unsigned short* src = vb + ((size_t)bh * 2048 + m0) * 64;
    unsigned short* dst = vbt + ((size_t)bh << 17) + m0;
    union { short8 v; unsigned short u[8]; } tmp;
    #pragma unroll
    for (int it = 0; it < 2; it++) {
        int idx = it * 256 + tid;
        int m = idx >> 3, c8 = (idx & 7) * 8;
        tmp.v = *(const short8*)(src + (size_t)m * 64 + c8);
        #pragma unroll
        for (int j = 0; j < 8; j++) t[c8 + j][m] = tmp.u[j];
    }
    __syncthreads();
    #pragma unroll
    for (int it = 0; it < 2; it++) {
        int idx = it * 256 + tid;
        int k = idx >> 3, c8 = (idx & 7) * 8;
        short8 v = *(const short8*)&t[k][c8];
        *(short8*)(dst + (size_t)k * 2048 + c8) = v;
    }
}

// ---------------------------------------------------------------------------
// qkv_gemm (m93-style 128x128 tile, BK=32), epilogue scatters q/k/v
// ---------------------------------------------------------------------------
__global__ __launch_bounds__(256) void qkv_gemm(
    const unsigned short* __restrict__ A, const unsigned short* __restrict__ Bt,
    unsigned short* __restrict__ qb, unsigned short* __restrict__ kb,
    unsigned short* __restrict__ vb)
{
    __shared__ __align__(16) unsigned short As[128 * 32];
    __shared__ __align__(16) unsigned short Bs[128 * 32];
    const int tid = threadIdx.x, wave = tid >> 6, lane = tid & 63;
    const int quad = lane >> 4, lr = lane & 15;
    const int wr = wave >> 1, wc = wave & 1;
    const int bm = blockIdx.y * 128, bn = blockIdx.x * 128;
    const int srow = wave * 32 + (lane >> 2);
    const int sblk = lane & 3;

    floatx4 acc[4][4];
    #pragma unroll
    for (int i = 0; i < 4; i++)
        #pragma unroll
        for (int j = 0; j < 4; j++) acc[i][j] = (floatx4)0.0f;

    for (int k0 = 0; k0 < 1024; k0 += 32) {
        #pragma unroll
        for (int t = 0; t < 2; t++) {
            int r = srow + t * 16;
            short8 va = *(const short8*)(A  + (size_t)(bm + r) * 1024 + k0 + sblk * 8);
            short8 vw = *(const short8*)(Bt + (size_t)(bn + r) * 1024 + k0 + sblk * 8);
            *(short8*)&As[r * 32 + sblk * 8] = va;
            *(short8*)&Bs[r * 32 + sblk * 8] = vw;
        }
        __syncthreads();
        short8 af[4], bfr[4];
        #pragma unroll
        for (int i = 0; i < 4; i++)
            af[i] = *(const short8*)&As[(wr * 64 + i * 16 + lr) * 32 + quad * 8];
        #pragma unroll
        for (int j = 0; j < 4; j++)
            bfr[j] = *(const short8*)&Bs[(wc * 64 + j * 16 + lr) * 32 + quad * 8];
        #pragma unroll
        for (int i = 0; i < 4; i++)
            #pragma unroll
            for (int j = 0; j < 4; j++)
                acc[i][j] = __builtin_amdgcn_mfma_f32_16x16x32_bf16(af[i], bfr[j], acc[i][j], 0, 0, 0);
        __syncthreads();
    }

    const int part = bn >> 10;
    unsigned short* __restrict__ dstb = (part == 0) ? qb : ((part == 1) ? kb : vb);
    const float sc = (part == 0) ? QSCALE : 1.0f;
    const int dbase = bn & 1023;
    #pragma unroll
    for (int i = 0; i < 4; i++)
        #pragma unroll
        for (int j = 0; j < 4; j++)
            #pragma unroll
            for (int r = 0; r < 4; r++) {
                int row = bm + wr * 64 + i * 16 + quad * 4 + r;
                int d   = dbase + wc * 64 + j * 16 + lr;
                int b = row >> 11, l = row & 2047;
                int flat = (l << 10) | d;
                int h = flat >> 17;
                int rem = flat & 131071;
                int l2 = rem >> 6, kk = rem & 63;
                dstb[((size_t)(b * 16 + h) * 2048 + l2) * 64 + kk] = f2bf(acc[i][j][r] * sc);
            }
}

__global__ __launch_bounds__(256) void out_gemm(
    const unsigned short* __restrict__ A, const unsigned short* __restrict__ Bt,
    float* __restrict__ C)
{
    __shared__ __align__(16) unsigned short As[128 * 32];
    __shared__ __align__(16) unsigned short Bs[128 * 32];
    const int tid = threadIdx.x, wave = tid >> 6, lane = tid & 63;
    const int quad = lane >> 4, lr = lane & 15;
    const int wr = wave >> 1, wc = wave & 1;
    const int bm = blockIdx.y * 128, bn = blockIdx.x * 128;
    const int srow = wave * 32 + (lane >> 2);
    const int sblk = lane & 3;

    floatx4 acc[4][4];
    #pragma unroll
    for (int i = 0; i < 4; i++)
        #pragma unroll
        for (int j = 0; j < 4; j++) acc[i][j] = (floatx4)0.0f;

    for (int k0 = 0; k0 < 1024; k0 += 32) {
        #pragma unroll
        for (int t = 0; t < 2; t++) {
            int r = srow + t * 16;
            short8 va = *(const short8*)(A  + (size_t)(bm + r) * 1024 + k0 + sblk * 8);
            short8 vw = *(const short8*)(Bt + (size_t)(bn + r) * 1024 + k0 + sblk * 8);
            *(short8*)&As[r * 32 + sblk * 8] = va;
            *(short8*)&Bs[r * 32 + sblk * 8] = vw;
        }
        __syncthreads();
        short8 af[4], bfr[4];
        #pragma unroll
        for (int i = 0; i < 4; i++)
            af[i] = *(const short8*)&As[(wr * 64 + i * 16 + lr) * 32 + quad * 8];
        #pragma unroll
        for (int j = 0; j < 4; j++)
            bfr[j] = *(const short8*)&Bs[(wc * 64 + j * 16 + lr) * 32 + quad * 8];
        #pragma unroll
        for (int i = 0; i < 4; i++)
            #pragma unroll
            for (int j = 0; j < 4; j++)
                acc[i][j] = __builtin_amdgcn_mfma_f32_16x16x32_bf16(af[i], bfr[j], acc[i][j], 0, 0, 0);
        __syncthreads();
    }
    #pragma unroll
    for (int i = 0; i < 4; i++)
        #pragma unroll
        for (int j = 0; j < 4; j++)
            #pragma unroll
            for (int r = 0; r < 4; r++) {
                int row = bm + wr * 64 + i * 16 + quad * 4 + r;
                int col = bn + wc * 64 + j * 16 + lr;
                C[(size_t)row * 1024 + col] = acc[i][j][r];
            }
}

// ---------------------------------------------------------------------------
// attn_denom: block = (b, 64 l x 64 m). Loops 16 heads; Q/K tiles staged
// swizzled in LDS; next head's tiles prefetched into registers. Stores
// reciprocal denom in transposed-C-tile order drpT[b][mt][lt][256].
// ---------------------------------------------------------------------------
__global__ __launch_bounds__(256, 4) void attn_denom(
    const unsigned short* __restrict__ qb, const unsigned short* __restrict__ kb,
    unsigned short* __restrict__ drpT)
{
    __shared__ __align__(16) unsigned short Qs[64 * 64];
    __shared__ __align__(16) unsigned short Ks[64 * 64];
    const int tid = threadIdx.x, wave = tid >> 6, lane = tid & 63;
    const int quad = lane >> 4, lr = lane & 15;
    const int M0 = blockIdx.x * 64, L0 = blockIdx.y * 64, b = blockIdx.z;
    const int srow = tid >> 3, sblk = tid & 7;       // rows srow, srow+32
    const int sphys = (sblk ^ (srow & 7)) * 8;

    floatx4 e[4];
    #pragma unroll
    for (int i = 0; i < 4; i++) e[i] = (floatx4)0.0f;

    {
        const size_t hb = ((size_t)(b * 16)) << 17;
        short8 q0 = *(const short8*)(qb + hb + (size_t)(L0 + srow) * 64 + sblk * 8);
        short8 q1 = *(const short8*)(qb + hb + (size_t)(L0 + srow + 32) * 64 + sblk * 8);
        short8 k0 = *(const short8*)(kb + hb + (size_t)(M0 + srow) * 64 + sblk * 8);
        short8 k1 = *(const short8*)(kb + hb + (size_t)(M0 + srow + 32) * 64 + sblk * 8);
        *(short8*)&Qs[srow * 64 + sphys] = q0;
        *(short8*)&Qs[(srow + 32) * 64 + sphys] = q1;
        *(short8*)&Ks[srow * 64 + sphys] = k0;
        *(short8*)&Ks[(srow + 32) * 64 + sphys] = k1;
    }
    __syncthreads();

    for (int h = 0; h < 16; h++) {
        short8 qn0, qn1, kn0, kn1;
        if (h < 15) {
            const size_t hb = ((size_t)(b * 16 + h + 1)) << 17;
            qn0 = *(const short8*)(qb + hb + (size_t)(L0 + srow) * 64 + sblk * 8);
            qn1 = *(const short8*)(qb + hb + (size_t)(L0 + srow + 32) * 64 + sblk * 8);
            kn0 = *(const short8*)(kb + hb + (size_t)(M0 + srow) * 64 + sblk * 8);
            kn1 = *(const short8*)(kb + hb + (size_t)(M0 + srow + 32) * 64 + sblk * 8);
        }
        const int rq = wave * 16 + lr;
        short8 qf0 = *(const short8*)&Qs[rq * 64 + ((quad) ^ (lr & 7)) * 8];
        short8 qf1 = *(const short8*)&Qs[rq * 64 + ((4 + quad) ^ (lr & 7)) * 8];
        #pragma unroll
        for (int mt = 0; mt < 4; mt++) {
            const int rk = mt * 16 + lr;
            short8 kf0 = *(const short8*)&Ks[rk * 64 + ((quad) ^ (lr & 7)) * 8];
            short8 kf1 = *(const short8*)&Ks[rk * 64 + ((4 + quad) ^ (lr & 7)) * 8];
            floatx4 s = (floatx4)0.0f;
            s = __builtin_amdgcn_mfma_f32_16x16x32_bf16(kf0, qf0, s, 0, 0, 0);
            s = __builtin_amdgcn_mfma_f32_16x16x32_bf16(kf1, qf1, s, 0, 0, 0);
            e[mt][0] += __builtin_amdgcn_exp2f(s[0]);
            e[mt][1] += __builtin_amdgcn_exp2f(s[1]);
            e[mt][2] += __builtin_amdgcn_exp2f(s[2]);
            e[mt][3] += __builtin_amdgcn_exp2f(s[3]);
        }
        __syncthreads();
        if (h < 15) {
            *(short8*)&Qs[srow * 64 + sphys] = qn0;
            *(short8*)&Qs[(srow + 32) * 64 + sphys] = qn1;
            *(short8*)&Ks[srow * 64 + sphys] = kn0;
            *(short8*)&Ks[(srow + 32) * 64 + sphys] = kn1;
            __syncthreads();
        }
    }
    #pragma unroll
    for (int mt = 0; mt < 4; mt++) {
        float r0 = __builtin_amdgcn_rcpf(e[mt][0]);
        float r1 = __builtin_amdgcn_rcpf(e[mt][1]);
        float r2 = __builtin_amdgcn_rcpf(e[mt][2]);
        float r3 = __builtin_amdgcn_rcpf(e[mt][3]);
        uint2 o;
        o.x = pack2bf(r0, r1);
        o.y = pack2bf(r2, r3);
        int mtg = (M0 >> 4) + mt;
        int ltg = (L0 >> 4) + wave;
        *(uint2*)(drpT + ((((size_t)b * 128 + mtg) * 128 + ltg) << 8) + lane * 4) = o;
    }
}

// ---------------------------------------------------------------------------
// attn_pv: block = (b, h, 64 l). Software-pipelined: body t does S(t) into
// Ps[t&1] and PV(t-1) from Ps[(t-1)&1] (independent streams), K double-
// buffered with register prefetch, drp tiles prefetched one step ahead.
// One barrier per 64-m step. Wave owns 16 l-rows (wave-private P).
// ---------------------------------------------------------------------------
__global__ __launch_bounds__(256, 4) void attn_pv(
    const unsigned short* __restrict__ qb, const unsigned short* __restrict__ kb,
    const unsigned short* __restrict__ vbt, const unsigned short* __restrict__ drpT,
    unsigned short* __restrict__ cb)
{
    __shared__ __align__(16) unsigned short Ks[2][64 * 64];  // 2 x 8 KB
    __shared__ __align__(16) unsigned short Ps[2][4][16 * 64]; // 2 x 8 KB, wave-private
    const int tid = threadIdx.x, wave = tid >> 6, lane = tid & 63;
    const int quad = lane >> 4, lr = lane & 15;
    const int L0 = blockIdx.x * 64, h = blockIdx.y, b = blockIdx.z;
    const size_t head = (size_t)(b * 16 + h);
    const unsigned short* qbase = qb + (head << 17);
    const unsigned short* kbase = kb + (head << 17);
    const unsigned short* vtb   = vbt + (head << 17);        // [64][2048]
    const int krow = tid >> 3, ksb = tid & 7;                // K stage rows krow, krow+32
    const int kphys = (ksb ^ (krow & 7)) * 8;
    const int e7 = lr & 7;
    const int ltg = (L0 >> 4) + wave;
    const size_t drp_lt_base = (((size_t)b * 128) * 128 + ltg) << 8;

    // Q B-fragments (rows L0 + wave*16 + lr), loaded once
    short8 qf0, qf1;
    {
        const unsigned short* qr = qbase + (size_t)(L0 + wave * 16 + lr) * 64;
        qf0 = *(const short8*)(qr + quad * 8);
        qf1 = *(const short8*)(qr + 32 + quad * 8);
    }

    floatx4 oacc[4];
    #pragma unroll
    for (int j = 0; j < 4; j++) oacc[j] = (floatx4)0.0f;

    // prologue: stage K(0), prefetch drp(0)
    uint2 dureg[4];
    {
        short8 a = *(const short8*)(kbase + (size_t)krow * 64 + ksb * 8);
        short8 c = *(const short8*)(kbase + (size_t)(krow + 32) * 64 + ksb * 8);
        *(short8*)&Ks[0][krow * 64 + kphys] = a;
        *(short8*)&Ks[0][(krow + 32) * 64 + kphys] = c;
        #pragma unroll
        for (int mt = 0; mt < 4; mt++)
            dureg[mt] = *(const uint2*)(drpT + drp_lt_base + ((size_t)mt << 15) + lane * 4);
    }
    __syncthreads();

    for (int t = 0; t <= 32; t++) {
        short8 nka, nkc;
        if (t < 31) {
            nka = *(const short8*)(kbase + (size_t)((t + 1) * 64 + krow) * 64 + ksb * 8);
            nkc = *(const short8*)(kbase + (size_t)((t + 1) * 64 + krow + 32) * 64 + ksb * 8);
        }
        if (t < 32) {
            // consume this step's drp, prefetch next step's
            uint2 duse[4];
            #pragma unroll
            for (int mt = 0; mt < 4; mt++) duse[mt] = dureg[mt];
            if (t < 31) {
                #pragma unroll
                for (int mt = 0; mt < 4; mt++)
                    dureg[mt] = *(const uint2*)(drpT + drp_lt_base +
                                 (((size_t)((t + 1) * 4 + mt)) << 15) + lane * 4);
            }
            // ---- S(t): S^T tiles mt 0..3, P -> Ps[t&1] (wave-private) ----
            const unsigned short* ksrc = &Ks[t & 1][0];
            unsigned short* pl = &Ps[t & 1][wave][0];
            #pragma unroll
            for (int mt = 0; mt < 4; mt++) {
                const int rk = mt * 16 + lr;
                short8 kf0 = *(const short8*)&ksrc[rk * 64 + (quad ^ e7) * 8];
                short8 kf1 = *(const short8*)&ksrc[rk * 64 + ((4 + quad) ^ e7) * 8];
                floatx4 s = (floatx4)0.0f;
                s = __builtin_amdgcn_mfma_f32_16x16x32_bf16(kf0, qf0, s, 0, 0, 0);
                s = __builtin_amdgcn_mfma_f32_16x16x32_bf16(kf1, qf1, s, 0, 0, 0);
                float r0 = __uint_as_float(duse[mt].x << 16);
                float r1 = __uint_as_float(duse[mt].x & 0xffff0000u);
                float r2 = __uint_as_float(duse[mt].y << 16);
                float r3 = __uint_as_float(duse[mt].y & 0xffff0000u);
                float p0 = __builtin_amdgcn_exp2f(s[0]) * r0;
                float p1 = __builtin_amdgcn_exp2f(s[1]) * r1;
                float p2 = __builtin_amdgcn_exp2f(s[2]) * r2;
                float p3 = __builtin_amdgcn_exp2f(s[3]) * r3;
                uint2 o;
                o.x = pack2bf(p0, p1);
                o.y = pack2bf(p2, p3);
                const int b16 = mt * 2 + (quad >> 1);
                *(uint2*)&pl[lr * 64 + (b16 ^ e7) * 8 + (quad & 1) * 4] = o;
            }
        }
        if (t > 0) {
            // ---- PV(t-1): wave-private P A-frags + V^T B-frags ----
            const int Mp = (t - 1) * 64;
            const unsigned short* pl = &Ps[(t - 1) & 1][wave][0];
            #pragma unroll
            for (int f = 0; f < 2; f++) {
                short8 pf = *(const short8*)&pl[lr * 64 + ((f * 4 + quad) ^ e7) * 8];
                #pragma unroll
                for (int j2 = 0; j2 < 4; j2++) {
                    short8 vf = *(const short8*)(vtb + (size_t)(j2 * 16 + lr) * 2048 + Mp + f * 32 + quad * 8);
                    oacc[j2] = __builtin_amdgcn_mfma_f32_16x16x32_bf16(pf, vf, oacc[j2], 0, 0, 0);
                }
            }
        }
        if (t < 31) {
            unsigned short* kdst = &Ks[(t + 1) & 1][0];
            *(short8*)&kdst[krow * 64 + kphys] = nka;
            *(short8*)&kdst[(krow + 32) * 64 + kphys] = nkc;
            __syncthreads();
        }
    }
    // epilogue: concat layout cb[b*2048 + l][h*64 + n]
    #pragma unroll
    for (int j2 = 0; j2 < 4; j2++)
        #pragma unroll
        for (int r = 0; r < 4; r++) {
            int row = L0 + wave * 16 + quad * 4 + r;
            int col = h * 64 + j2 * 16 + lr;
            cb[(size_t)(b * 2048 + row) * 1024 + col] = f2bf(oacc[j2][r]);
        }
}

extern "C" void kernel_launch(void* const* d_in, const int* in_sizes, int n_in,
                              void* d_out, int out_size, void* d_ws, size_t ws_size,
                              hipStream_t stream) {
    const float* x    = (const float*)d_in[0];   // [4,2048,1024]
    const float* wqkv = (const float*)d_in[1];   // [1024,3072]
    const float* wo   = (const float*)d_in[2];   // [1024,1024]
    float* out = (float*)d_out;                  // [4,2048,1024] fp32

    // workspace: 100,663,296 bytes with overlays
    unsigned short* W = (unsigned short*)d_ws;
    unsigned short* qb   = W;                    // [4,16,2048,64] pre-scaled Q
    unsigned short* kb   = W + 8388608;          // [4,16,2048,64]
    unsigned short* vbt  = W + 16777216;         // [4,16,64,2048] V^T
    unsigned short* drpT = W + 25165824;         // [4][128mt][128lt][256] recip denom
    unsigned short* cb   = W + 41943040;         // [8192,1024] concat
    // overlays (lifetime-disjoint):
    unsigned short* xb    = drpT;                // bf16 x   (dead before denom)
    unsigned short* wqkvT = drpT + 8388608;      // bf16 wqkv^T [3072][1024]
    unsigned short* vb    = cb;                  // V row-major (dead before pv)
    unsigned short* woT   = drpT;                // bf16 wo^T [1024][1024] (after pv)

    cvt_bf16  <<<4096, 256, 0, stream>>>(x, xb, 1048576);
    tcvt      <<<dim3(48, 16), 256, 0, stream>>>(wqkv, wqkvT, 1024, 3072);
    qkv_gemm  <<<dim3(24, 64), 256, 0, stream>>>(xb, wqkvT, qb, kb, vb);
    vtrans    <<<dim3(32, 64), 256, 0, stream>>>(vb, vbt);
    attn_denom<<<dim3(32, 32, 4), 256, 0, stream>>>(qb, kb, drpT);
    attn_pv   <<<dim3(32, 16, 4), 256, 0, stream>>>(qb, kb, vbt, drpT, cb);
    tcvt      <<<dim3(16, 16), 256, 0, stream>>>(wo, woT, 1024, 1024);
    out_gemm  <<<dim3(8, 64), 256, 0, stream>>>(cb, woT, out);
}

// Round 6
// 427.205 us; speedup vs baseline: 1.2551x; 1.2551x over previous
//
#include <hip/hip_runtime.h>
#include <hip/hip_bf16.h>
#include <stdint.h>

typedef __attribute__((ext_vector_type(8))) short short8;
typedef __attribute__((ext_vector_type(4))) float floatx4;

// Q pre-scale: 0.125 (1/sqrt(K)) * log2(e), so exp(s/8) == exp2(q'.k)
#define QSCALE 0.18033688f

__device__ __forceinline__ unsigned short f2bf(float f) {
    unsigned int u = __float_as_uint(f);
    u += 0x7fffu + ((u >> 16) & 1u);
    return (unsigned short)(u >> 16);
}
__device__ __forceinline__ unsigned int pack2bf(float a, float b) {
    __hip_bfloat162 h = __float22bfloat162_rn(make_float2(a, b));
    return *reinterpret_cast<unsigned int*>(&h);
}

// async global->LDS, 16B per lane; LDS dst must be wave-uniform base + lane*16
__device__ __forceinline__ void async16(const void* g, void* l) {
    __builtin_amdgcn_global_load_lds(
        (const __attribute__((address_space(1))) unsigned int*)g,
        (__attribute__((address_space(3))) unsigned int*)l, 16, 0, 0);
}

// ---------------------------------------------------------------------------
// cvt: fp32 -> bf16, 8 elements/thread
// ---------------------------------------------------------------------------
__global__ __launch_bounds__(256) void cvt_bf16(const float* __restrict__ src,
                                                unsigned short* __restrict__ dst, int n8) {
    int i = blockIdx.x * 256 + threadIdx.x;
    if (i >= n8) return;
    const float4 a = ((const float4*)src)[2 * i];
    const float4 b = ((const float4*)src)[2 * i + 1];
    ushort4 lo, hi;
    lo.x = f2bf(a.x); lo.y = f2bf(a.y); lo.z = f2bf(a.z); lo.w = f2bf(a.w);
    hi.x = f2bf(b.x); hi.y = f2bf(b.y); hi.z = f2bf(b.z); hi.w = f2bf(b.w);
    ((ushort4*)dst)[2 * i] = lo;
    ((ushort4*)dst)[2 * i + 1] = hi;
}

// ---------------------------------------------------------------------------
// tcvt: fp32 [R][C] -> bf16 [C][R]  (64x64 tiles via LDS)
// ---------------------------------------------------------------------------
__global__ __launch_bounds__(256) void tcvt(const float* __restrict__ src,
                                            unsigned short* __restrict__ dst, int R, int C) {
    __shared__ unsigned short t[64][72];
    const int tid = threadIdx.x;
    const int r0 = blockIdx.y * 64, c0 = blockIdx.x * 64;
    #pragma unroll
    for (int it = 0; it < 4; it++) {
        int idx = it * 256 + tid;
        int rr = idx >> 4, cc = (idx & 15) * 4;
        float4 v = *(const float4*)(src + (size_t)(r0 + rr) * C + c0 + cc);
        t[cc + 0][rr] = f2bf(v.x);
        t[cc + 1][rr] = f2bf(v.y);
        t[cc + 2][rr] = f2bf(v.z);
        t[cc + 3][rr] = f2bf(v.w);
    }
    __syncthreads();
    #pragma unroll
    for (int it = 0; it < 2; it++) {
        int idx = it * 256 + tid;
        int cc = idx >> 3, r8 = (idx & 7) * 8;
        short8 v = *(const short8*)&t[cc][r8];
        *(short8*)(dst + (size_t)(c0 + cc) * R + r0 + r8) = v;
    }
}

// ---------------------------------------------------------------------------
// vtrans: vb[bh][2048][64] -> vbt[bh][64][2048]  (64x64 tiles via LDS)
// ---------------------------------------------------------------------------
__global__ __launch_bounds__(256) void vtrans(const unsigned short* __restrict__ vb,
                                              unsigned short* __restrict__ vbt) {
    __shared__ unsigned short t[64][72];
    const int tid = threadIdx.x;
    const int bh = blockIdx.y, m0 = blockIdx.x * 64;
    const unsigned short* src = vb + ((size_t)bh * 2048 + m0) * 64;
    unsigned short* dst = vbt + ((size_t)bh << 17) + m0;
    union { short8 v; unsigned short u[8]; } tmp;
    #pragma unroll
    for (int it = 0; it < 2; it++) {
        int idx = it * 256 + tid;
        int m = idx >> 3, c8 = (idx & 7) * 8;
        tmp.v = *(const short8*)(src + (size_t)m * 64 + c8);
        #pragma unroll
        for (int j = 0; j < 8; j++) t[c8 + j][m] = tmp.u[j];
    }
    __syncthreads();
    #pragma unroll
    for (int it = 0; it < 2; it++) {
        int idx = it * 256 + tid;
        int k = idx >> 3, c8 = (idx & 7) * 8;
        short8 v = *(const short8*)&t[k][c8];
        *(short8*)(dst + (size_t)k * 2048 + c8) = v;
    }
}

// ---------------------------------------------------------------------------
// qkv_gemm (128x128 tile, BK=32) with async global->LDS staging (16B/lane).
// Staging layout: thread (wave, lane) of sub-step t deposits at
// As byte offset wave*2048 + t*1024 + lane*16  == rows [wave*32+t*16, +16).
// Epilogue scatters q/k/v per the faithful reshape quirk.
// ---------------------------------------------------------------------------
__global__ __launch_bounds__(256) void qkv_gemm(
    const unsigned short* __restrict__ A, const unsigned short* __restrict__ Bt,
    unsigned short* __restrict__ qb, unsigned short* __restrict__ kb,
    unsigned short* __restrict__ vb)
{
    __shared__ __align__(16) unsigned short As[128 * 32];
    __shared__ __align__(16) unsigned short Bs[128 * 32];
    const int tid = threadIdx.x, wave = tid >> 6, lane = tid & 63;
    const int quad = lane >> 4, lr = lane & 15;
    const int wr = wave >> 1, wc = wave & 1;
    const int bm = blockIdx.y * 128, bn = blockIdx.x * 128;
    const int lrow = lane >> 2, lcol = (lane & 3) * 8;

    floatx4 acc[4][4];
    #pragma unroll
    for (int i = 0; i < 4; i++)
        #pragma unroll
        for (int j = 0; j < 4; j++) acc[i][j] = (floatx4)0.0f;

    for (int k0 = 0; k0 < 1024; k0 += 32) {
        #pragma unroll
        for (int t = 0; t < 2; t++) {
            const int rbase = wave * 32 + t * 16;       // wave-uniform
            const int r = rbase + lrow;
            async16(A  + (size_t)(bm + r) * 1024 + k0 + lcol, &As[rbase * 32]);
            async16(Bt + (size_t)(bn + r) * 1024 + k0 + lcol, &Bs[rbase * 32]);
        }
        __syncthreads();
        short8 af[4], bfr[4];
        #pragma unroll
        for (int i = 0; i < 4; i++)
            af[i] = *(const short8*)&As[(wr * 64 + i * 16 + lr) * 32 + quad * 8];
        #pragma unroll
        for (int j = 0; j < 4; j++)
            bfr[j] = *(const short8*)&Bs[(wc * 64 + j * 16 + lr) * 32 + quad * 8];
        #pragma unroll
        for (int i = 0; i < 4; i++)
            #pragma unroll
            for (int j = 0; j < 4; j++)
                acc[i][j] = __builtin_amdgcn_mfma_f32_16x16x32_bf16(af[i], bfr[j], acc[i][j], 0, 0, 0);
        __syncthreads();
    }

    const int part = bn >> 10;
    unsigned short* __restrict__ dstb = (part == 0) ? qb : ((part == 1) ? kb : vb);
    const float sc = (part == 0) ? QSCALE : 1.0f;
    const int dbase = bn & 1023;
    #pragma unroll
    for (int i = 0; i < 4; i++)
        #pragma unroll
        for (int j = 0; j < 4; j++)
            #pragma unroll
            for (int r = 0; r < 4; r++) {
                int row = bm + wr * 64 + i * 16 + quad * 4 + r;
                int d   = dbase + wc * 64 + j * 16 + lr;
                int b = row >> 11, l = row & 2047;
                int flat = (l << 10) | d;
                int h = flat >> 17;
                int rem = flat & 131071;
                int l2 = rem >> 6, kk = rem & 63;
                dstb[((size_t)(b * 16 + h) * 2048 + l2) * 64 + kk] = f2bf(acc[i][j][r] * sc);
            }
}

__global__ __launch_bounds__(256) void out_gemm(
    const unsigned short* __restrict__ A, const unsigned short* __restrict__ Bt,
    float* __restrict__ C)
{
    __shared__ __align__(16) unsigned short As[128 * 32];
    __shared__ __align__(16) unsigned short Bs[128 * 32];
    const int tid = threadIdx.x, wave = tid >> 6, lane = tid & 63;
    const int quad = lane >> 4, lr = lane & 15;
    const int wr = wave >> 1, wc = wave & 1;
    const int bm = blockIdx.y * 128, bn = blockIdx.x * 128;
    const int lrow = lane >> 2, lcol = (lane & 3) * 8;

    floatx4 acc[4][4];
    #pragma unroll
    for (int i = 0; i < 4; i++)
        #pragma unroll
        for (int j = 0; j < 4; j++) acc[i][j] = (floatx4)0.0f;

    for (int k0 = 0; k0 < 1024; k0 += 32) {
        #pragma unroll
        for (int t = 0; t < 2; t++) {
            const int rbase = wave * 32 + t * 16;
            const int r = rbase + lrow;
            async16(A  + (size_t)(bm + r) * 1024 + k0 + lcol, &As[rbase * 32]);
            async16(Bt + (size_t)(bn + r) * 1024 + k0 + lcol, &Bs[rbase * 32]);
        }
        __syncthreads();
        short8 af[4], bfr[4];
        #pragma unroll
        for (int i = 0; i < 4; i++)
            af[i] = *(const short8*)&As[(wr * 64 + i * 16 + lr) * 32 + quad * 8];
        #pragma unroll
        for (int j = 0; j < 4; j++)
            bfr[j] = *(const short8*)&Bs[(wc * 64 + j * 16 + lr) * 32 + quad * 8];
        #pragma unroll
        for (int i = 0; i < 4; i++)
            #pragma unroll
            for (int j = 0; j < 4; j++)
                acc[i][j] = __builtin_amdgcn_mfma_f32_16x16x32_bf16(af[i], bfr[j], acc[i][j], 0, 0, 0);
        __syncthreads();
    }
    #pragma unroll
    for (int i = 0; i < 4; i++)
        #pragma unroll
        for (int j = 0; j < 4; j++)
            #pragma unroll
            for (int r = 0; r < 4; r++) {
                int row = bm + wr * 64 + i * 16 + quad * 4 + r;
                int col = bn + wc * 64 + j * 16 + lr;
                C[(size_t)row * 1024 + col] = acc[i][j][r];
            }
}

// ---------------------------------------------------------------------------
// attn_denom: block = (b, 64 l x 64 m). Loops 16 heads; Q/K tiles staged
// swizzled in LDS; next head's tiles prefetched into registers. Stores
// reciprocal denom in transposed-C-tile order drpT[b][mt][lt][256].
// ---------------------------------------------------------------------------
__global__ __launch_bounds__(256, 4) void attn_denom(
    const unsigned short* __restrict__ qb, const unsigned short* __restrict__ kb,
    unsigned short* __restrict__ drpT)
{
    __shared__ __align__(16) unsigned short Qs[64 * 64];
    __shared__ __align__(16) unsigned short Ks[64 * 64];
    const int tid = threadIdx.x, wave = tid >> 6, lane = tid & 63;
    const int quad = lane >> 4, lr = lane & 15;
    const int M0 = blockIdx.x * 64, L0 = blockIdx.y * 64, b = blockIdx.z;
    const int srow = tid >> 3, sblk = tid & 7;       // rows srow, srow+32
    const int sphys = (sblk ^ (srow & 7)) * 8;

    floatx4 e[4];
    #pragma unroll
    for (int i = 0; i < 4; i++) e[i] = (floatx4)0.0f;

    {
        const size_t hb = ((size_t)(b * 16)) << 17;
        short8 q0 = *(const short8*)(qb + hb + (size_t)(L0 + srow) * 64 + sblk * 8);
        short8 q1 = *(const short8*)(qb + hb + (size_t)(L0 + srow + 32) * 64 + sblk * 8);
        short8 k0 = *(const short8*)(kb + hb + (size_t)(M0 + srow) * 64 + sblk * 8);
        short8 k1 = *(const short8*)(kb + hb + (size_t)(M0 + srow + 32) * 64 + sblk * 8);
        *(short8*)&Qs[srow * 64 + sphys] = q0;
        *(short8*)&Qs[(srow + 32) * 64 + sphys] = q1;
        *(short8*)&Ks[srow * 64 + sphys] = k0;
        *(short8*)&Ks[(srow + 32) * 64 + sphys] = k1;
    }
    __syncthreads();

    for (int h = 0; h < 16; h++) {
        short8 qn0, qn1, kn0, kn1;
        if (h < 15) {
            const size_t hb = ((size_t)(b * 16 + h + 1)) << 17;
            qn0 = *(const short8*)(qb + hb + (size_t)(L0 + srow) * 64 + sblk * 8);
            qn1 = *(const short8*)(qb + hb + (size_t)(L0 + srow + 32) * 64 + sblk * 8);
            kn0 = *(const short8*)(kb + hb + (size_t)(M0 + srow) * 64 + sblk * 8);
            kn1 = *(const short8*)(kb + hb + (size_t)(M0 + srow + 32) * 64 + sblk * 8);
        }
        const int rq = wave * 16 + lr;
        short8 qf0 = *(const short8*)&Qs[rq * 64 + ((quad) ^ (lr & 7)) * 8];
        short8 qf1 = *(const short8*)&Qs[rq * 64 + ((4 + quad) ^ (lr & 7)) * 8];
        #pragma unroll
        for (int mt = 0; mt < 4; mt++) {
            const int rk = mt * 16 + lr;
            short8 kf0 = *(const short8*)&Ks[rk * 64 + ((quad) ^ (lr & 7)) * 8];
            short8 kf1 = *(const short8*)&Ks[rk * 64 + ((4 + quad) ^ (lr & 7)) * 8];
            floatx4 s = (floatx4)0.0f;
            s = __builtin_amdgcn_mfma_f32_16x16x32_bf16(kf0, qf0, s, 0, 0, 0);
            s = __builtin_amdgcn_mfma_f32_16x16x32_bf16(kf1, qf1, s, 0, 0, 0);
            e[mt][0] += __builtin_amdgcn_exp2f(s[0]);
            e[mt][1] += __builtin_amdgcn_exp2f(s[1]);
            e[mt][2] += __builtin_amdgcn_exp2f(s[2]);
            e[mt][3] += __builtin_amdgcn_exp2f(s[3]);
        }
        __syncthreads();
        if (h < 15) {
            *(short8*)&Qs[srow * 64 + sphys] = qn0;
            *(short8*)&Qs[(srow + 32) * 64 + sphys] = qn1;
            *(short8*)&Ks[srow * 64 + sphys] = kn0;
            *(short8*)&Ks[(srow + 32) * 64 + sphys] = kn1;
            __syncthreads();
        }
    }
    #pragma unroll
    for (int mt = 0; mt < 4; mt++) {
        float r0 = __builtin_amdgcn_rcpf(e[mt][0]);
        float r1 = __builtin_amdgcn_rcpf(e[mt][1]);
        float r2 = __builtin_amdgcn_rcpf(e[mt][2]);
        float r3 = __builtin_amdgcn_rcpf(e[mt][3]);
        uint2 o;
        o.x = pack2bf(r0, r1);
        o.y = pack2bf(r2, r3);
        int mtg = (M0 >> 4) + mt;
        int ltg = (L0 >> 4) + wave;
        *(uint2*)(drpT + ((((size_t)b * 128 + mtg) * 128 + ltg) << 8) + lane * 4) = o;
    }
}

// ---------------------------------------------------------------------------
// attn_pv (R4 structure + V/drp register prefetch): block = (b, h, 128 l).
// m-loop in 64-steps; K double-buffered in LDS with register prefetch; all 8
// V^T fragments prefetched at step top (consumed after S phase); drp tiles
// prefetched one phase ahead. Wave owns l-rows [32w,32w+32) for both S and PV
// (wave-private P, no S->PV barrier). One barrier per step.
// ---------------------------------------------------------------------------
__global__ __launch_bounds__(256, 4) void attn_pv(
    const unsigned short* __restrict__ qb, const unsigned short* __restrict__ kb,
    const unsigned short* __restrict__ vbt, const unsigned short* __restrict__ drpT,
    unsigned short* __restrict__ cb)
{
    __shared__ __align__(16) unsigned short Ks[2][64 * 64];  // 2 x 8 KB
    __shared__ __align__(16) unsigned short Ps[128 * 64];    // 16 KB
    const int tid = threadIdx.x, wave = tid >> 6, lane = tid & 63;
    const int quad = lane >> 4, lr = lane & 15;
    const int L0 = blockIdx.x * 128, h = blockIdx.y, b = blockIdx.z;
    const size_t head = (size_t)(b * 16 + h);
    const unsigned short* qbase = qb + (head << 17);
    const unsigned short* kbase = kb + (head << 17);
    const unsigned short* vtb   = vbt + (head << 17);        // [64][2048]
    const int krow = tid >> 3, ksb = tid & 7;                // K stage rows krow, krow+32
    const int kphys = (ksb ^ (krow & 7)) * 8;
    const int e7 = lr & 15 & 7;
    // drp base for this wave's two l-tiles (ltg = (L0>>4)+wave*2 + j)
    const unsigned short* dbase = drpT + (((size_t)b * 128 * 128 + ((L0 >> 4) + wave * 2)) << 8) + lane * 4;

    // Q B-fragments (rows L0 + wave*32 + j*16 + lr), loaded once
    short8 qf[2][2];
    #pragma unroll
    for (int j = 0; j < 2; j++) {
        const unsigned short* qr = qbase + (size_t)(L0 + wave * 32 + j * 16 + lr) * 64;
        qf[j][0] = *(const short8*)(qr + quad * 8);
        qf[j][1] = *(const short8*)(qr + 32 + quad * 8);
    }

    floatx4 oacc[2][4];
    #pragma unroll
    for (int i = 0; i < 2; i++)
        #pragma unroll
        for (int j = 0; j < 4; j++) oacc[i][j] = (floatx4)0.0f;

    // prologue: stage K(0); prefetch drp(0)
    uint2 dunext[4][2];
    {
        short8 a = *(const short8*)(kbase + (size_t)krow * 64 + ksb * 8);
        short8 c = *(const short8*)(kbase + (size_t)(krow + 32) * 64 + ksb * 8);
        *(short8*)&Ks[0][krow * 64 + kphys] = a;
        *(short8*)&Ks[0][(krow + 32) * 64 + kphys] = c;
        #pragma unroll
        for (int mt = 0; mt < 4; mt++)
            #pragma unroll
            for (int j = 0; j < 2; j++)
                dunext[mt][j] = *(const uint2*)(dbase + ((size_t)mt << 15) + (j << 8));
    }
    __syncthreads();

    for (int t = 0; t < 32; t++) {
        const int M0 = t * 64;
        // ---- top-of-step loads: K(t+1) and all 8 V fragments of this step ----
        short8 nka, nkc;
        if (t < 31) {
            nka = *(const short8*)(kbase + (size_t)(M0 + 64 + krow) * 64 + ksb * 8);
            nkc = *(const short8*)(kbase + (size_t)(M0 + 64 + krow + 32) * 64 + ksb * 8);
        }
        short8 vfr[2][4];
        #pragma unroll
        for (int f = 0; f < 2; f++)
            #pragma unroll
            for (int j2 = 0; j2 < 4; j2++)
                vfr[f][j2] = *(const short8*)(vtb + (size_t)(j2 * 16 + lr) * 2048 + M0 + f * 32 + quad * 8);

        // ---- S phase: S^T tiles (mt 0..3) x (j 0..1), P -> wave-private LDS ----
        const unsigned short* ksrc = &Ks[t & 1][0];
        #pragma unroll
        for (int mt = 0; mt < 4; mt++) {
            const int rk = mt * 16 + lr;
            short8 kf0 = *(const short8*)&ksrc[rk * 64 + (quad ^ e7) * 8];
            short8 kf1 = *(const short8*)&ksrc[rk * 64 + ((4 + quad) ^ e7) * 8];
            #pragma unroll
            for (int j = 0; j < 2; j++) {
                uint2 du = dunext[mt][j];
                floatx4 s = (floatx4)0.0f;
                s = __builtin_amdgcn_mfma_f32_16x16x32_bf16(kf0, qf[j][0], s, 0, 0, 0);
                s = __builtin_amdgcn_mfma_f32_16x16x32_bf16(kf1, qf[j][1], s, 0, 0, 0);
                float r0 = __uint_as_float(du.x << 16);
                float r1 = __uint_as_float(du.x & 0xffff0000u);
                float r2 = __uint_as_float(du.y << 16);
                float r3 = __uint_as_float(du.y & 0xffff0000u);
                float p0 = __builtin_amdgcn_exp2f(s[0]) * r0;
                float p1 = __builtin_amdgcn_exp2f(s[1]) * r1;
                float p2 = __builtin_amdgcn_exp2f(s[2]) * r2;
                float p3 = __builtin_amdgcn_exp2f(s[3]) * r3;
                uint2 o;
                o.x = pack2bf(p0, p1);
                o.y = pack2bf(p2, p3);
                const int l_loc = wave * 32 + j * 16 + lr;
                const int lb16 = mt * 2 + (quad >> 1);
                *(uint2*)&Ps[l_loc * 64 + (lb16 ^ e7) * 8 + (quad & 1) * 4] = o;
            }
        }
        // ---- prefetch next step's drp (consumed next iteration) ----
        if (t < 31) {
            #pragma unroll
            for (int mt = 0; mt < 4; mt++)
                #pragma unroll
                for (int j = 0; j < 2; j++)
                    dunext[mt][j] = *(const uint2*)(dbase + (((size_t)((t + 1) * 4 + mt)) << 15) + (j << 8));
        }
        // ---- PV phase: wave-private P A-frags + prefetched V frags ----
        #pragma unroll
        for (int f = 0; f < 2; f++) {
            short8 pf[2];
            #pragma unroll
            for (int i2 = 0; i2 < 2; i2++) {
                const int lrow = wave * 32 + i2 * 16 + lr;
                pf[i2] = *(const short8*)&Ps[lrow * 64 + ((f * 4 + quad) ^ e7) * 8];
            }
            #pragma unroll
            for (int j2 = 0; j2 < 4; j2++)
                #pragma unroll
                for (int i2 = 0; i2 < 2; i2++)
                    oacc[i2][j2] = __builtin_amdgcn_mfma_f32_16x16x32_bf16(pf[i2], vfr[f][j2], oacc[i2][j2], 0, 0, 0);
        }
        // ---- store prefetched K into the other buffer; single barrier ----
        if (t < 31) {
            unsigned short* kdst = &Ks[(t + 1) & 1][0];
            *(short8*)&kdst[krow * 64 + kphys] = nka;
            *(short8*)&kdst[(krow + 32) * 64 + kphys] = nkc;
            __syncthreads();
        }
    }
    // epilogue: concat layout cb[b*2048 + l][h*64 + n]
    #pragma unroll
    for (int i2 = 0; i2 < 2; i2++)
        #pragma unroll
        for (int j2 = 0; j2 < 4; j2++)
            #pragma unroll
            for (int r = 0; r < 4; r++) {
                int row = L0 + wave * 32 + i2 * 16 + quad * 4 + r;
                int col = h * 64 + j2 * 16 + lr;
                cb[(size_t)(b * 2048 + row) * 1024 + col] = f2bf(oacc[i2][j2][r]);
            }
}

extern "C" void kernel_launch(void* const* d_in, const int* in_sizes, int n_in,
                              void* d_out, int out_size, void* d_ws, size_t ws_size,
                              hipStream_t stream) {
    const float* x    = (const float*)d_in[0];   // [4,2048,1024]
    const float* wqkv = (const float*)d_in[1];   // [1024,3072]
    const float* wo   = (const float*)d_in[2];   // [1024,1024]
    float* out = (float*)d_out;                  // [4,2048,1024] fp32

    // workspace: 100,663,296 bytes with overlays
    unsigned short* W = (unsigned short*)d_ws;
    unsigned short* qb   = W;                    // [4,16,2048,64] pre-scaled Q
    unsigned short* kb   = W + 8388608;          // [4,16,2048,64]
    unsigned short* vbt  = W + 16777216;         // [4,16,64,2048] V^T
    unsigned short* drpT = W + 25165824;         // [4][128mt][128lt][256] recip denom
    unsigned short* cb   = W + 41943040;         // [8192,1024] concat
    // overlays (lifetime-disjoint):
    unsigned short* xb    = drpT;                // bf16 x   (dead before denom)
    unsigned short* wqkvT = drpT + 8388608;      // bf16 wqkv^T [3072][1024]
    unsigned short* vb    = cb;                  // V row-major (dead before pv)
    unsigned short* woT   = drpT;                // bf16 wo^T [1024][1024] (after pv)

    cvt_bf16  <<<4096, 256, 0, stream>>>(x, xb, 1048576);
    tcvt      <<<dim3(48, 16), 256, 0, stream>>>(wqkv, wqkvT, 1024, 3072);
    qkv_gemm  <<<dim3(24, 64), 256, 0, stream>>>(xb, wqkvT, qb, kb, vb);
    vtrans    <<<dim3(32, 64), 256, 0, stream>>>(vb, vbt);
    attn_denom<<<dim3(32, 32, 4), 256, 0, stream>>>(qb, kb, drpT);
    attn_pv   <<<dim3(16, 16, 4), 256, 0, stream>>>(qb, kb, vbt, drpT, cb);
    tcvt      <<<dim3(16, 16), 256, 0, stream>>>(wo, woT, 1024, 1024);
    out_gemm  <<<dim3(8, 64), 256, 0, stream>>>(cb, woT, out);
}